// Round 7
// baseline (352.211 us; speedup 1.0000x reference)
//
#include <hip/hip_runtime.h>
#include <hip/hip_fp16.h>
#include <math.h>

#define N_NODES 100000
#define N_EDGES 1600000
#define N_GRAPHS 256
#define T_CAPS 16
#define D_CH 64
#define BN_EPS 1e-5f
#define NSPLIT 8
#define CHUNK 32
#define FIX_SCALE 33554432.0f   // 2^25
#define HIST_T 200000           // N_EDGES / 8
#define SCAT_T 400000           // N_EDGES / 4

__device__ __forceinline__ float waveReduceSum(float v) {
    for (int m = 32; m >= 1; m >>= 1) v += __shfl_xor(v, m, 64);
    return v;
}

// ---- setup: pack=0, zero bn_sums/hsum/xsum, WT transpose, gstart binary search ----
__global__ void setup_kernel(unsigned long long* pack, float* bn_sums, float* hsum, float* xsum,
                             const float* __restrict__ W, float* __restrict__ WT,
                             const int* __restrict__ batch, int* __restrict__ gstart) {
    int idx = blockIdx.x * blockDim.x + threadIdx.x;
    if (idx < N_NODES) pack[idx] = 0ULL;
    if (idx < 128) bn_sums[idx] = 0.0f;
    if (idx < N_GRAPHS * D_CH) { hsum[idx] = 0.0f; xsum[idx] = 0.0f; }
    if (idx < T_CAPS * 64 * 64) {
        int t = idx >> 12, rem = idx & 4095, o = rem >> 6, i = rem & 63;
        WT[idx] = W[t * 4096 + i * 64 + o];
    }
    if (idx <= N_GRAPHS) {
        int lo = 0, hi = N_NODES;
        while (lo < hi) { int mid = (lo + hi) >> 1; if (batch[mid] < idx) lo = mid + 1; else hi = mid; }
        gstart[idx] = lo;
    }
}

// ---- BN stats + fp16 staging of x ----
__global__ void bn_stats_kernel(const float* __restrict__ x, float* __restrict__ sums,
                                __half2* __restrict__ x16) {
    int pr = threadIdx.x & 31;   // channel pair 0..31
    int rg = threadIdx.x >> 5;   // 0..7
    int c0 = pr * 2;
    float s0 = 0, q0 = 0, s1 = 0, q1 = 0;
    for (int r = blockIdx.x * 8 + rg; r < N_NODES; r += gridDim.x * 8) {
        float2 v = *(const float2*)(x + (size_t)r * 64 + c0);
        s0 += v.x; q0 += v.x * v.x;
        s1 += v.y; q1 += v.y * v.y;
        x16[(size_t)r * 32 + pr] = __floats2half2_rn(v.x, v.y);
    }
    __shared__ float ls[2][8][64];
    ls[0][rg][c0] = s0; ls[0][rg][c0 + 1] = s1;
    ls[1][rg][c0] = q0; ls[1][rg][c0 + 1] = q1;
    __syncthreads();
    if (threadIdx.x < 64) {
        float a = 0.0f, b = 0.0f;
        for (int i = 0; i < 8; i++) { a += ls[0][i][threadIdx.x]; b += ls[1][i][threadIdx.x]; }
        atomicAdd(&sums[threadIdx.x], a);
        atomicAdd(&sums[64 + threadIdx.x], b);
    }
}

// ---- histogram, ILP=8: 8 independent packed atomics in flight per thread ----
__global__ void hist_kernel(const int* __restrict__ col, const float* __restrict__ ew,
                            unsigned long long* __restrict__ pack, int* __restrict__ rank) {
    int tid = blockIdx.x * blockDim.x + threadIdx.x;
    if (tid >= HIST_T) return;
    int c[8]; unsigned fx[8];
    #pragma unroll
    for (int i = 0; i < 8; i++) {
        int e = tid + i * HIST_T;
        c[i] = col[e];
        fx[i] = __float2uint_rn(ew[e] * FIX_SCALE);
    }
    unsigned long long old[8];
    #pragma unroll
    for (int i = 0; i < 8; i++)
        old[i] = atomicAdd(&pack[c[i]], (1ULL << 32) | (unsigned long long)fx[i]);
    #pragma unroll
    for (int i = 0; i < 8; i++)
        rank[tid + i * HIST_T] = (int)(old[i] >> 32);
}

// ---- scan (1024/block) + dinv decode + BN affine ab ----
__global__ void scan1_kernel(const unsigned long long* __restrict__ pack, int* __restrict__ off,
                             int* __restrict__ bsum, float* __restrict__ dinv,
                             const float* __restrict__ sums, const float* __restrict__ gamma,
                             const float* __restrict__ beta, float* __restrict__ ab) {
    __shared__ int lds[256];
    int tid = threadIdx.x;
    int base = blockIdx.x * 1024 + tid * 4;
    int c[4];
    #pragma unroll
    for (int i = 0; i < 4; i++) {
        if (base + i < N_NODES) {
            unsigned long long pv = pack[base + i];
            c[i] = (int)(pv >> 32);
            float d = 1.0f + (float)(unsigned)(pv & 0xFFFFFFFFULL) * (1.0f / FIX_SCALE);
            dinv[base + i] = 1.0f / sqrtf(d);
        } else c[i] = 0;
    }
    if (blockIdx.x == 0 && tid < 64) {
        float mu = sums[tid] * (1.0f / N_NODES);
        float var = sums[64 + tid] * (1.0f / N_NODES) - mu * mu;
        float inv = 1.0f / sqrtf(var + BN_EPS);
        float a = inv * gamma[tid];
        ab[tid] = a;
        ab[64 + tid] = beta[tid] - mu * a;
    }
    int tsum = c[0] + c[1] + c[2] + c[3];
    lds[tid] = tsum;
    __syncthreads();
    for (int d = 1; d < 256; d <<= 1) {
        int v = (tid >= d) ? lds[tid - d] : 0;
        __syncthreads();
        lds[tid] += v;
        __syncthreads();
    }
    int excl = lds[tid] - tsum;
    if (base + 0 < N_NODES) off[base + 0] = excl;
    if (base + 1 < N_NODES) off[base + 1] = excl + c[0];
    if (base + 2 < N_NODES) off[base + 2] = excl + c[0] + c[1];
    if (base + 3 < N_NODES) off[base + 3] = excl + c[0] + c[1] + c[2];
    if (tid == 255) bsum[blockIdx.x] = lds[255];
}

// ---- scan of block sums (nb <= 128), one block ----
__global__ void scan2_kernel(int* __restrict__ bsum, int nb) {
    __shared__ int lds[128];
    int tid = threadIdx.x;
    int v = (tid < nb) ? bsum[tid] : 0;
    lds[tid] = v;
    __syncthreads();
    for (int d = 1; d < 128; d <<= 1) {
        int u = (tid >= d) ? lds[tid - d] : 0;
        __syncthreads();
        lds[tid] += u;
        __syncthreads();
    }
    if (tid < nb) bsum[tid] = lds[tid] - v;
}

__global__ void scan3_kernel(int* __restrict__ off, const int* __restrict__ bsum) {
    int idx = blockIdx.x * blockDim.x + threadIdx.x;
    if (idx < N_NODES) off[idx] = off[idx] + bsum[idx >> 10];
    if (idx == 0) off[N_NODES] = N_EDGES;
}

// ---- scatter (atomic-free), ILP=4: pos = off[col] + rank; rec[pos] = (row, coef) ----
__global__ void scatter_kernel(const int* __restrict__ row, const int* __restrict__ col,
                               const float* __restrict__ ew, const int* __restrict__ rank,
                               const float* __restrict__ dinv, const int* __restrict__ off,
                               int2* __restrict__ rec) {
    int tid = blockIdx.x * blockDim.x + threadIdx.x;
    if (tid >= SCAT_T) return;
    #pragma unroll
    for (int i = 0; i < 4; i++) {
        int e = tid + i * SCAT_T;
        int c = col[e], r = row[e];
        float coef = dinv[r] * ew[e] * dinv[c];
        int pos = off[c] + rank[e];
        rec[pos] = make_int2(r, __float_as_int(coef));
    }
}

// ---- gather (fp16 x): h = a*(sum coef*x) + b*(sum coef); 4-way unroll ----
__global__ void h_gather_kernel(const int2* __restrict__ rec, const int* __restrict__ off,
                                const float* __restrict__ dinv, const __half* __restrict__ x16,
                                const float* __restrict__ ab, float* __restrict__ h) {
    int n = blockIdx.x * 4 + (threadIdx.x >> 6);
    int ch = threadIdx.x & 63;
    int e0 = off[n], e1 = off[n + 1];
    float dv = dinv[n];
    float cself = dv * dv;
    float acc0 = cself * __half2float(x16[(size_t)n * 64 + ch]);
    float acc1 = 0.0f, acc2 = 0.0f, acc3 = 0.0f;
    float csr = cself;
    int e = e0;
    for (; e + 4 <= e1; e += 4) {
        int2 r0 = rec[e], r1 = rec[e + 1], r2 = rec[e + 2], r3 = rec[e + 3];
        float c0 = __int_as_float(r0.y), c1 = __int_as_float(r1.y);
        float c2 = __int_as_float(r2.y), c3 = __int_as_float(r3.y);
        float x0 = __half2float(x16[(size_t)r0.x * 64 + ch]);
        float x1 = __half2float(x16[(size_t)r1.x * 64 + ch]);
        float x2 = __half2float(x16[(size_t)r2.x * 64 + ch]);
        float x3 = __half2float(x16[(size_t)r3.x * 64 + ch]);
        acc0 += c0 * x0; acc1 += c1 * x1; acc2 += c2 * x2; acc3 += c3 * x3;
        csr += c0 + c1 + c2 + c3;
    }
    for (; e < e1; ++e) {
        int2 rc = rec[e];
        float c = __int_as_float(rc.y);
        acc0 += c * __half2float(x16[(size_t)rc.x * 64 + ch]);
        csr += c;
    }
    float acc = (acc0 + acc1) + (acc2 + acc3);
    h[(size_t)n * 64 + ch] = ab[ch] * acc + ab[64 + ch] * csr;
}

// ---- per-graph sums of x16 and of h (atomic partials) ----
__global__ void gsum_kernel(const __half* __restrict__ x16, const float* __restrict__ h,
                            const int* __restrict__ gstart, float* __restrict__ xsum,
                            float* __restrict__ hsum) {
    int g = blockIdx.x / NSPLIT, sp = blockIdx.x % NSPLIT;
    int s0g = gstart[g], s1g = gstart[g + 1];
    int len = s1g - s0g;
    int q = (len + NSPLIT - 1) / NSPLIT;
    int a0 = s0g + sp * q, a1 = min(s1g, a0 + q);
    int ch = threadIdx.x & 63, rg = threadIdx.x >> 6;
    float ax = 0.0f, ah = 0.0f;
    for (int n = a0 + rg; n < a1; n += 4) {
        ax += __half2float(x16[(size_t)n * 64 + ch]);
        ah += h[(size_t)n * 64 + ch];
    }
    __shared__ float lx[4][64], lh[4][64];
    lx[rg][ch] = ax; lh[rg][ch] = ah;
    __syncthreads();
    if (threadIdx.x < 64) {
        int c = threadIdx.x;
        float sx = lx[0][c] + lx[1][c] + lx[2][c] + lx[3][c];
        float sh = lh[0][c] + lh[1][c] + lh[2][c] + lh[3][c];
        atomicAdd(&xsum[g * 64 + c], sx);
        atomicAdd(&hsum[g * 64 + c], sh);
    }
}

// ---- fused routing: thread-parallel logit dot + in-register softmax + accumulate ----
__global__ void ka_fused_kernel(const float* __restrict__ h, const int* __restrict__ gstart,
                                const float* __restrict__ wva, const float* __restrict__ bva,
                                const float* __restrict__ wvb, const float* __restrict__ bvb,
                                float* __restrict__ hc_part, float* __restrict__ csum_part,
                                int mode) {
    int g = blockIdx.x / NSPLIT, sp = blockIdx.x % NSPLIT;
    int s0g = gstart[g], s1g = gstart[g + 1];
    int len = s1g - s0g;
    int q = (len + NSPLIT - 1) / NSPLIT;
    int s0 = s0g + sp * q, s1 = min(s1g, s0 + q);
    int tid = threadIdx.x;
    int d = tid & 63, tg = tid >> 6;
    int t = tid & 15, kh = tid >> 4;

    __shared__ float hlds[CHUNK][65];
    __shared__ float wa[16][65];
    __shared__ float wb[16][65];
    __shared__ float clds[CHUNK][17];
    __shared__ float bvl[2][16];

    for (int i = tid; i < 16 * 64; i += 256) {
        int tt = i >> 6, dd = i & 63;
        wa[tt][dd] = wva[(g * 16 + tt) * 64 + dd];
        if (mode) wb[tt][dd] = wvb[(g * 16 + tt) * 64 + dd];
    }
    if (tid < 16) { bvl[0][tid] = bva[g * 16 + tid]; bvl[1][tid] = mode ? bvb[g * 16 + tid] : 0.0f; }
    for (int i = tid; i < CHUNK * 65; i += 256) ((float*)hlds)[i] = 0.0f;
    __syncthreads();

    float acc0 = 0, acc1 = 0, acc2 = 0, acc3 = 0;
    float cs0 = 0, cs1 = 0, cs2 = 0, cs3 = 0;

    for (int n0 = s0; n0 < s1; n0 += CHUNK) {
        int nn = min(CHUNK, s1 - n0);
        #pragma unroll
        for (int j = 0; j < 8; j++) {
            int k = tg * 8 + j;
            if (k < nn) hlds[k][d] = h[(size_t)(n0 + k) * 64 + d];
        }
        __syncthreads();
        int k0 = kh, k1 = kh + 16;
        float u0, u1;
        if (mode) {
            float a0 = bvl[0][t], a1 = bvl[0][t], b0 = bvl[1][t], b1 = bvl[1][t];
            for (int dd = 0; dd < 64; dd++) {
                float wav = wa[t][dd], wbv = wb[t][dd];
                float h0 = hlds[k0][dd], h1 = hlds[k1][dd];
                a0 += h0 * wav; a1 += h1 * wav;
                b0 += h0 * wbv; b1 += h1 * wbv;
            }
            u0 = a0 + b0; u1 = a1 + b1;
        } else {
            float a0 = bvl[0][t], a1 = bvl[0][t];
            for (int dd = 0; dd < 64; dd++) {
                float wav = wa[t][dd];
                a0 += hlds[k0][dd] * wav; a1 += hlds[k1][dd] * wav;
            }
            u0 = a0; u1 = a1;
        }
        float m0 = u0, m1 = u1;
        #pragma unroll
        for (int msk = 1; msk < 16; msk <<= 1) {
            m0 = fmaxf(m0, __shfl_xor(m0, msk, 64));
            m1 = fmaxf(m1, __shfl_xor(m1, msk, 64));
        }
        float e0 = expf(u0 - m0), e1 = expf(u1 - m1);
        float z0 = e0, z1 = e1;
        #pragma unroll
        for (int msk = 1; msk < 16; msk <<= 1) {
            z0 += __shfl_xor(z0, msk, 64);
            z1 += __shfl_xor(z1, msk, 64);
        }
        if (k0 < nn) clds[k0][t] = e0 / z0;
        if (k1 < nn) clds[k1][t] = e1 / z1;
        __syncthreads();
        for (int k = 0; k < nn; k++) {
            float hv = hlds[k][d];
            float c0 = clds[k][tg * 4 + 0], c1 = clds[k][tg * 4 + 1];
            float c2 = clds[k][tg * 4 + 2], c3 = clds[k][tg * 4 + 3];
            acc0 += c0 * hv; acc1 += c1 * hv; acc2 += c2 * hv; acc3 += c3 * hv;
            if (d == 0) { cs0 += c0; cs1 += c1; cs2 += c2; cs3 += c3; }
        }
        __syncthreads();
    }
    size_t base = ((size_t)(sp * N_GRAPHS + g) * 16 + tg * 4) * 64 + d;
    hc_part[base] = acc0; hc_part[base + 64] = acc1;
    hc_part[base + 128] = acc2; hc_part[base + 192] = acc3;
    if (d == 0) {
        int cb = (sp * N_GRAPHS + g) * 16 + tg * 4;
        csum_part[cb + 0] = cs0; csum_part[cb + 1] = cs1;
        csum_part[cb + 2] = cs2; csum_part[cb + 3] = cs3;
    }
}

// ---- kb: one wave per (g,t). mode 0: uniform-softmax path; 1: mid; 2: final+out ----
__global__ void kb_kernel(const float* __restrict__ hsum, const float* __restrict__ hc_part,
                          const float* __restrict__ csum_part, const float* __restrict__ W,
                          const float* __restrict__ WT, const float* __restrict__ bias,
                          const float* __restrict__ xsum, const float* __restrict__ ab,
                          const int* __restrict__ gstart, float* __restrict__ wv,
                          float* __restrict__ bv, float* __restrict__ out, int mode) {
    int wid = blockIdx.x * 4 + (threadIdx.x >> 6);
    int lane = threadIdx.x & 63;
    int g = wid >> 4, t = wid & 15;
    const float* Wt = W + t * 4096;
    float cnt = (float)(gstart[g + 1] - gstart[g]);
    float s;
    if (mode == 0) {
        const float* hr = hsum + g * 64;
        float acc = cnt * bias[t * 64 + lane];
        for (int i = 0; i < 64; i++) acc += hr[i] * Wt[i * 64 + lane];
        s = acc * (1.0f / 16.0f);
    } else {
        float csum = 0.0f;
        #pragma unroll
        for (int sp = 0; sp < NSPLIT; sp++) csum += csum_part[(sp * N_GRAPHS + g) * 16 + t];
        float acc = csum * bias[t * 64 + lane];
        for (int i = 0; i < 64; i++) {
            float hci = 0.0f;
            #pragma unroll
            for (int sp = 0; sp < NSPLIT; sp++)
                hci += hc_part[((size_t)(sp * N_GRAPHS + g) * 16 + t) * 64 + i];
            acc += hci * Wt[i * 64 + lane];
        }
        s = acc;
        if (mode == 2) {
            float xm = ab[lane] * xsum[g * 64 + lane] / fmaxf(cnt, 1.0f) + ab[64 + lane];
            s += xm;
        }
    }
    float sq = waveReduceSum(s * s);
    float scale = (sq / (1.0f + sq)) / sqrtf(sq + 1e-16f);
    float v = scale * s;
    if (mode == 2) {
        float tot = waveReduceSum(1.0f / fabsf(v));
        if (lane == 0) out[wid] = 1.0f / tot;
    } else {
        __shared__ float vlds[4][64];
        int w = threadIdx.x >> 6;
        vlds[w][lane] = v;
        __syncthreads();
        const float* WTt = WT + t * 4096;
        float acc = 0.0f;
        for (int o = 0; o < 64; o++) acc += WTt[o * 64 + lane] * vlds[w][o];
        wv[(size_t)wid * 64 + lane] = acc;
        float b = waveReduceSum(bias[t * 64 + lane] * v);
        if (lane == 0) bv[wid] = b;
    }
}

extern "C" void kernel_launch(void* const* d_in, const int* in_sizes, int n_in,
                              void* d_out, int out_size, void* d_ws, size_t ws_size,
                              hipStream_t stream) {
    const float* x     = (const float*)d_in[0];
    const int*   ei    = (const int*)d_in[1];
    const float* ew    = (const float*)d_in[2];
    const int*   batch = (const int*)d_in[3];
    const float* gamma = (const float*)d_in[4];
    const float* beta  = (const float*)d_in[5];
    const float* W     = (const float*)d_in[6];
    const float* bias  = (const float*)d_in[7];
    float* out = (float*)d_out;

    const int* row = ei;
    const int* col = ei + N_EDGES;

    char* basep = (char*)d_ws;
    int2* rec = (int2*)basep;                              basep += sizeof(int2) * N_EDGES;
    unsigned long long* pack = (unsigned long long*)basep; basep += 8ULL * N_NODES;
    __half2* x16 = (__half2*)basep;                        basep += 2ULL * N_NODES * D_CH;
    float* p = (float*)basep;
    float* h        = p; p += (size_t)N_NODES * D_CH;
    float* hc_part  = p; p += (size_t)NSPLIT * N_GRAPHS * T_CAPS * D_CH;
    float* csum_part= p; p += NSPLIT * N_GRAPHS * T_CAPS;
    float* wva      = p; p += N_GRAPHS * T_CAPS * D_CH;
    float* bva      = p; p += N_GRAPHS * T_CAPS;
    float* wvb      = p; p += N_GRAPHS * T_CAPS * D_CH;
    float* bvb      = p; p += N_GRAPHS * T_CAPS;
    float* WT       = p; p += T_CAPS * 64 * 64;
    float* dinv     = p; p += N_NODES;
    float* bn_sums  = p; p += 128;
    float* ab       = p; p += 128;
    float* hsum     = p; p += N_GRAPHS * D_CH;
    float* xsum     = p; p += N_GRAPHS * D_CH;
    int*   ip       = (int*)p;
    int*   off      = ip; ip += N_NODES + 1;
    int*   rank     = ip; ip += N_EDGES;
    int*   bsum     = ip; ip += 128;
    int*   gstart   = ip; ip += N_GRAPHS + 1;

    const int nscan = (N_NODES + 1023) / 1024;

    setup_kernel<<<(N_NODES + 255) / 256, 256, 0, stream>>>(pack, bn_sums, hsum, xsum,
                                                             W, WT, batch, gstart);
    bn_stats_kernel<<<512, 256, 0, stream>>>(x, bn_sums, x16);
    hist_kernel<<<(HIST_T + 255) / 256, 256, 0, stream>>>(col, ew, pack, rank);
    scan1_kernel<<<nscan, 256, 0, stream>>>(pack, off, bsum, dinv, bn_sums, gamma, beta, ab);
    scan2_kernel<<<1, 128, 0, stream>>>(bsum, nscan);
    scan3_kernel<<<(N_NODES + 255) / 256, 256, 0, stream>>>(off, bsum);
    scatter_kernel<<<(SCAT_T + 255) / 256, 256, 0, stream>>>(row, col, ew, rank, dinv, off, rec);
    h_gather_kernel<<<N_NODES / 4, 256, 0, stream>>>(rec, off, dinv, (const __half*)x16, ab, h);
    gsum_kernel<<<N_GRAPHS * NSPLIT, 256, 0, stream>>>((const __half*)x16, h, gstart, xsum, hsum);

    kb_kernel<<<N_GRAPHS * T_CAPS / 4, 256, 0, stream>>>(hsum, hc_part, csum_part, W, WT, bias,
                                                          xsum, ab, gstart, wva, bva, out, 0);
    ka_fused_kernel<<<N_GRAPHS * NSPLIT, 256, 0, stream>>>(h, gstart, wva, bva, wvb, bvb,
                                                            hc_part, csum_part, 0);
    kb_kernel<<<N_GRAPHS * T_CAPS / 4, 256, 0, stream>>>(hsum, hc_part, csum_part, W, WT, bias,
                                                          xsum, ab, gstart, wvb, bvb, out, 1);
    ka_fused_kernel<<<N_GRAPHS * NSPLIT, 256, 0, stream>>>(h, gstart, wva, bva, wvb, bvb,
                                                            hc_part, csum_part, 1);
    kb_kernel<<<N_GRAPHS * T_CAPS / 4, 256, 0, stream>>>(hsum, hc_part, csum_part, W, WT, bias,
                                                          xsum, ab, gstart, wva, bva, out, 2);
}

// Round 8
// 336.052 us; speedup vs baseline: 1.0481x; 1.0481x over previous
//
#include <hip/hip_runtime.h>
#include <hip/hip_fp16.h>
#include <math.h>

#define N_NODES 100000
#define N_EDGES 1600000
#define N_GRAPHS 256
#define T_CAPS 16
#define D_CH 64
#define BN_EPS 1e-5f
#define NSPLIT 8
#define CHUNK 32
#define NPART 8
#define NBN 512
#define FIX_SCALE 33554432.0f   // 2^25
#define HIST_BLOCKS (N_EDGES / 256)

__device__ __forceinline__ float waveReduceSum(float v) {
    for (int m = 32; m >= 1; m >>= 1) v += __shfl_xor(v, m, 64);
    return v;
}

// ---- setup: pack[8][N]=0, zero bn_sums/hsum/xsum, WT transpose, gstart ----
__global__ void setup_kernel(unsigned long long* pack, float* bn_sums, float* hsum, float* xsum,
                             const float* __restrict__ W, float* __restrict__ WT,
                             const int* __restrict__ batch, int* __restrict__ gstart) {
    int idx = blockIdx.x * blockDim.x + threadIdx.x;
    if (idx < NPART * N_NODES) pack[idx] = 0ULL;
    if (idx < 128) bn_sums[idx] = 0.0f;
    if (idx < N_GRAPHS * D_CH) { hsum[idx] = 0.0f; xsum[idx] = 0.0f; }
    if (idx < T_CAPS * 64 * 64) {
        int t = idx >> 12, rem = idx & 4095, o = rem >> 6, i = rem & 63;
        WT[idx] = W[t * 4096 + i * 64 + o];
    }
    if (idx <= N_GRAPHS) {
        int lo = 0, hi = N_NODES;
        while (lo < hi) { int mid = (lo + hi) >> 1; if (batch[mid] < idx) lo = mid + 1; else hi = mid; }
        gstart[idx] = lo;
    }
}

// ---- heterogeneous: blocks [0,HIST_BLOCKS) do partitioned histogram;
//      blocks [HIST_BLOCKS, +NBN) do BN stats + fp16 staging ----
__global__ void histbn_kernel(const int* __restrict__ col, const float* __restrict__ ew,
                              unsigned long long* __restrict__ pack, int* __restrict__ rank,
                              const float* __restrict__ x, float* __restrict__ sums,
                              __half2* __restrict__ x16) {
    int b = blockIdx.x;
    if (b < HIST_BLOCKS) {
        int e = b * 256 + threadIdx.x;
        int c = col[e];
        unsigned fx = __float2uint_rn(ew[e] * FIX_SCALE);
        size_t slot = (size_t)(b & (NPART - 1)) * N_NODES + c;
        unsigned long long old = atomicAdd(&pack[slot], (1ULL << 32) | (unsigned long long)fx);
        rank[e] = (int)(old >> 32);
    } else {
        int bb = b - HIST_BLOCKS;
        int pr = threadIdx.x & 31;
        int rg = threadIdx.x >> 5;
        int c0 = pr * 2;
        float s0 = 0, q0 = 0, s1 = 0, q1 = 0;
        for (int r = bb * 8 + rg; r < N_NODES; r += NBN * 8) {
            float2 v = *(const float2*)(x + (size_t)r * 64 + c0);
            s0 += v.x; q0 += v.x * v.x;
            s1 += v.y; q1 += v.y * v.y;
            x16[(size_t)r * 32 + pr] = __floats2half2_rn(v.x, v.y);
        }
        __shared__ float ls[2][8][64];
        ls[0][rg][c0] = s0; ls[0][rg][c0 + 1] = s1;
        ls[1][rg][c0] = q0; ls[1][rg][c0 + 1] = q1;
        __syncthreads();
        if (threadIdx.x < 64) {
            float a = 0.0f, bsum = 0.0f;
            for (int i = 0; i < 8; i++) { a += ls[0][i][threadIdx.x]; bsum += ls[1][i][threadIdx.x]; }
            atomicAdd(&sums[threadIdx.x], a);
            atomicAdd(&sums[64 + threadIdx.x], bsum);
        }
    }
}

// ---- scan over total counts (1024/block) + per-partition local prefix poff +
//      dinv decode + BN affine ab ----
__global__ void scan1_kernel(const unsigned long long* __restrict__ pack, int* __restrict__ off,
                             int* __restrict__ bsum, int* __restrict__ poff,
                             float* __restrict__ dinv, const float* __restrict__ sums,
                             const float* __restrict__ gamma, const float* __restrict__ beta,
                             float* __restrict__ ab) {
    __shared__ int lds[256];
    int tid = threadIdx.x;
    int base = blockIdx.x * 1024 + tid * 4;
    int tot[4];
    #pragma unroll
    for (int i = 0; i < 4; i++) {
        int c = base + i;
        if (c < N_NODES) {
            unsigned run = 0;
            unsigned long long low_total = 0;
            #pragma unroll
            for (int p = 0; p < NPART; p++) {
                unsigned long long pv = pack[(size_t)p * N_NODES + c];
                poff[(size_t)p * N_NODES + c] = (int)run;
                run += (unsigned)(pv >> 32);
                low_total += (pv & 0xFFFFFFFFULL);
            }
            tot[i] = (int)run;
            float d = 1.0f + (float)low_total * (1.0f / FIX_SCALE);
            dinv[c] = 1.0f / sqrtf(d);
        } else tot[i] = 0;
    }
    if (blockIdx.x == 0 && tid < 64) {
        float mu = sums[tid] * (1.0f / N_NODES);
        float var = sums[64 + tid] * (1.0f / N_NODES) - mu * mu;
        float inv = 1.0f / sqrtf(var + BN_EPS);
        float a = inv * gamma[tid];
        ab[tid] = a;
        ab[64 + tid] = beta[tid] - mu * a;
    }
    int tsum = tot[0] + tot[1] + tot[2] + tot[3];
    lds[tid] = tsum;
    __syncthreads();
    for (int d = 1; d < 256; d <<= 1) {
        int v = (tid >= d) ? lds[tid - d] : 0;
        __syncthreads();
        lds[tid] += v;
        __syncthreads();
    }
    int excl = lds[tid] - tsum;
    if (base + 0 < N_NODES) off[base + 0] = excl;
    if (base + 1 < N_NODES) off[base + 1] = excl + tot[0];
    if (base + 2 < N_NODES) off[base + 2] = excl + tot[0] + tot[1];
    if (base + 3 < N_NODES) off[base + 3] = excl + tot[0] + tot[1] + tot[2];
    if (tid == 255) bsum[blockIdx.x] = lds[255];
}

// ---- scan of block sums (nb <= 128), one block ----
__global__ void scan2_kernel(int* __restrict__ bsum, int nb) {
    __shared__ int lds[128];
    int tid = threadIdx.x;
    int v = (tid < nb) ? bsum[tid] : 0;
    lds[tid] = v;
    __syncthreads();
    for (int d = 1; d < 128; d <<= 1) {
        int u = (tid >= d) ? lds[tid - d] : 0;
        __syncthreads();
        lds[tid] += u;
        __syncthreads();
    }
    if (tid < nb) bsum[tid] = lds[tid] - v;
}

// ---- finalize off and fold global offset into poff ----
__global__ void scan3_kernel(int* __restrict__ off, const int* __restrict__ bsum,
                             int* __restrict__ poff) {
    int idx = blockIdx.x * blockDim.x + threadIdx.x;
    if (idx < N_NODES) {
        int o = off[idx] + bsum[idx >> 10];
        off[idx] = o;
        #pragma unroll
        for (int p = 0; p < NPART; p++) poff[(size_t)p * N_NODES + idx] += o;
    }
    if (idx == 0) off[N_NODES] = N_EDGES;
}

// ---- scatter (atomic-free): pos = poff[p][col] + rank; rec[pos] = (row, coef) ----
__global__ void scatter_kernel(const int* __restrict__ row, const int* __restrict__ col,
                               const float* __restrict__ ew, const int* __restrict__ rank,
                               const float* __restrict__ dinv, const int* __restrict__ poff,
                               int2* __restrict__ rec) {
    int e = blockIdx.x * blockDim.x + threadIdx.x;
    if (e >= N_EDGES) return;
    int c = col[e], r = row[e];
    int p = (e >> 8) & (NPART - 1);
    float coef = dinv[r] * ew[e] * dinv[c];
    int pos = poff[(size_t)p * N_NODES + c] + rank[e];
    rec[pos] = make_int2(r, __float_as_int(coef));
}

// ---- gather (fp16 x): h = a*(sum coef*x) + b*(sum coef); 4-way unroll ----
__global__ void h_gather_kernel(const int2* __restrict__ rec, const int* __restrict__ off,
                                const float* __restrict__ dinv, const __half* __restrict__ x16,
                                const float* __restrict__ ab, float* __restrict__ h) {
    int n = blockIdx.x * 4 + (threadIdx.x >> 6);
    int ch = threadIdx.x & 63;
    int e0 = off[n], e1 = off[n + 1];
    float dv = dinv[n];
    float cself = dv * dv;
    float acc0 = cself * __half2float(x16[(size_t)n * 64 + ch]);
    float acc1 = 0.0f, acc2 = 0.0f, acc3 = 0.0f;
    float csr = cself;
    int e = e0;
    for (; e + 4 <= e1; e += 4) {
        int2 r0 = rec[e], r1 = rec[e + 1], r2 = rec[e + 2], r3 = rec[e + 3];
        float c0 = __int_as_float(r0.y), c1 = __int_as_float(r1.y);
        float c2 = __int_as_float(r2.y), c3 = __int_as_float(r3.y);
        float x0 = __half2float(x16[(size_t)r0.x * 64 + ch]);
        float x1 = __half2float(x16[(size_t)r1.x * 64 + ch]);
        float x2 = __half2float(x16[(size_t)r2.x * 64 + ch]);
        float x3 = __half2float(x16[(size_t)r3.x * 64 + ch]);
        acc0 += c0 * x0; acc1 += c1 * x1; acc2 += c2 * x2; acc3 += c3 * x3;
        csr += c0 + c1 + c2 + c3;
    }
    for (; e < e1; ++e) {
        int2 rc = rec[e];
        float c = __int_as_float(rc.y);
        acc0 += c * __half2float(x16[(size_t)rc.x * 64 + ch]);
        csr += c;
    }
    float acc = (acc0 + acc1) + (acc2 + acc3);
    h[(size_t)n * 64 + ch] = ab[ch] * acc + ab[64 + ch] * csr;
}

// ---- per-graph sums of x16 and of h (atomic partials) ----
__global__ void gsum_kernel(const __half* __restrict__ x16, const float* __restrict__ h,
                            const int* __restrict__ gstart, float* __restrict__ xsum,
                            float* __restrict__ hsum) {
    int g = blockIdx.x / NSPLIT, sp = blockIdx.x % NSPLIT;
    int s0g = gstart[g], s1g = gstart[g + 1];
    int len = s1g - s0g;
    int q = (len + NSPLIT - 1) / NSPLIT;
    int a0 = s0g + sp * q, a1 = min(s1g, a0 + q);
    int ch = threadIdx.x & 63, rg = threadIdx.x >> 6;
    float ax = 0.0f, ah = 0.0f;
    for (int n = a0 + rg; n < a1; n += 4) {
        ax += __half2float(x16[(size_t)n * 64 + ch]);
        ah += h[(size_t)n * 64 + ch];
    }
    __shared__ float lx[4][64], lh[4][64];
    lx[rg][ch] = ax; lh[rg][ch] = ah;
    __syncthreads();
    if (threadIdx.x < 64) {
        int c = threadIdx.x;
        float sx = lx[0][c] + lx[1][c] + lx[2][c] + lx[3][c];
        float sh = lh[0][c] + lh[1][c] + lh[2][c] + lh[3][c];
        atomicAdd(&xsum[g * 64 + c], sx);
        atomicAdd(&hsum[g * 64 + c], sh);
    }
}

// ---- fused routing: thread-parallel logit dot + in-register softmax + accumulate ----
__global__ void ka_fused_kernel(const float* __restrict__ h, const int* __restrict__ gstart,
                                const float* __restrict__ wva, const float* __restrict__ bva,
                                const float* __restrict__ wvb, const float* __restrict__ bvb,
                                float* __restrict__ hc_part, float* __restrict__ csum_part,
                                int mode) {
    int g = blockIdx.x / NSPLIT, sp = blockIdx.x % NSPLIT;
    int s0g = gstart[g], s1g = gstart[g + 1];
    int len = s1g - s0g;
    int q = (len + NSPLIT - 1) / NSPLIT;
    int s0 = s0g + sp * q, s1 = min(s1g, s0 + q);
    int tid = threadIdx.x;
    int d = tid & 63, tg = tid >> 6;
    int t = tid & 15, kh = tid >> 4;

    __shared__ float hlds[CHUNK][65];
    __shared__ float wa[16][65];
    __shared__ float wb[16][65];
    __shared__ float clds[CHUNK][17];
    __shared__ float bvl[2][16];

    for (int i = tid; i < 16 * 64; i += 256) {
        int tt = i >> 6, dd = i & 63;
        wa[tt][dd] = wva[(g * 16 + tt) * 64 + dd];
        if (mode) wb[tt][dd] = wvb[(g * 16 + tt) * 64 + dd];
    }
    if (tid < 16) { bvl[0][tid] = bva[g * 16 + tid]; bvl[1][tid] = mode ? bvb[g * 16 + tid] : 0.0f; }
    for (int i = tid; i < CHUNK * 65; i += 256) ((float*)hlds)[i] = 0.0f;
    __syncthreads();

    float acc0 = 0, acc1 = 0, acc2 = 0, acc3 = 0;
    float cs0 = 0, cs1 = 0, cs2 = 0, cs3 = 0;

    for (int n0 = s0; n0 < s1; n0 += CHUNK) {
        int nn = min(CHUNK, s1 - n0);
        #pragma unroll
        for (int j = 0; j < 8; j++) {
            int k = tg * 8 + j;
            if (k < nn) hlds[k][d] = h[(size_t)(n0 + k) * 64 + d];
        }
        __syncthreads();
        int k0 = kh, k1 = kh + 16;
        float u0, u1;
        if (mode) {
            float a0 = bvl[0][t], a1 = bvl[0][t], b0 = bvl[1][t], b1 = bvl[1][t];
            for (int dd = 0; dd < 64; dd++) {
                float wav = wa[t][dd], wbv = wb[t][dd];
                float h0 = hlds[k0][dd], h1 = hlds[k1][dd];
                a0 += h0 * wav; a1 += h1 * wav;
                b0 += h0 * wbv; b1 += h1 * wbv;
            }
            u0 = a0 + b0; u1 = a1 + b1;
        } else {
            float a0 = bvl[0][t], a1 = bvl[0][t];
            for (int dd = 0; dd < 64; dd++) {
                float wav = wa[t][dd];
                a0 += hlds[k0][dd] * wav; a1 += hlds[k1][dd] * wav;
            }
            u0 = a0; u1 = a1;
        }
        float m0 = u0, m1 = u1;
        #pragma unroll
        for (int msk = 1; msk < 16; msk <<= 1) {
            m0 = fmaxf(m0, __shfl_xor(m0, msk, 64));
            m1 = fmaxf(m1, __shfl_xor(m1, msk, 64));
        }
        float e0 = expf(u0 - m0), e1 = expf(u1 - m1);
        float z0 = e0, z1 = e1;
        #pragma unroll
        for (int msk = 1; msk < 16; msk <<= 1) {
            z0 += __shfl_xor(z0, msk, 64);
            z1 += __shfl_xor(z1, msk, 64);
        }
        if (k0 < nn) clds[k0][t] = e0 / z0;
        if (k1 < nn) clds[k1][t] = e1 / z1;
        __syncthreads();
        for (int k = 0; k < nn; k++) {
            float hv = hlds[k][d];
            float c0 = clds[k][tg * 4 + 0], c1 = clds[k][tg * 4 + 1];
            float c2 = clds[k][tg * 4 + 2], c3 = clds[k][tg * 4 + 3];
            acc0 += c0 * hv; acc1 += c1 * hv; acc2 += c2 * hv; acc3 += c3 * hv;
            if (d == 0) { cs0 += c0; cs1 += c1; cs2 += c2; cs3 += c3; }
        }
        __syncthreads();
    }
    size_t base = ((size_t)(sp * N_GRAPHS + g) * 16 + tg * 4) * 64 + d;
    hc_part[base] = acc0; hc_part[base + 64] = acc1;
    hc_part[base + 128] = acc2; hc_part[base + 192] = acc3;
    if (d == 0) {
        int cb = (sp * N_GRAPHS + g) * 16 + tg * 4;
        csum_part[cb + 0] = cs0; csum_part[cb + 1] = cs1;
        csum_part[cb + 2] = cs2; csum_part[cb + 3] = cs3;
    }
}

// ---- kb: one wave per (g,t). mode 0: uniform-softmax path; 1: mid; 2: final+out ----
__global__ void kb_kernel(const float* __restrict__ hsum, const float* __restrict__ hc_part,
                          const float* __restrict__ csum_part, const float* __restrict__ W,
                          const float* __restrict__ WT, const float* __restrict__ bias,
                          const float* __restrict__ xsum, const float* __restrict__ ab,
                          const int* __restrict__ gstart, float* __restrict__ wv,
                          float* __restrict__ bv, float* __restrict__ out, int mode) {
    int wid = blockIdx.x * 4 + (threadIdx.x >> 6);
    int lane = threadIdx.x & 63;
    int g = wid >> 4, t = wid & 15;
    const float* Wt = W + t * 4096;
    float cnt = (float)(gstart[g + 1] - gstart[g]);
    float s;
    if (mode == 0) {
        const float* hr = hsum + g * 64;
        float acc = cnt * bias[t * 64 + lane];
        for (int i = 0; i < 64; i++) acc += hr[i] * Wt[i * 64 + lane];
        s = acc * (1.0f / 16.0f);
    } else {
        float csum = 0.0f;
        #pragma unroll
        for (int sp = 0; sp < NSPLIT; sp++) csum += csum_part[(sp * N_GRAPHS + g) * 16 + t];
        float acc = csum * bias[t * 64 + lane];
        for (int i = 0; i < 64; i++) {
            float hci = 0.0f;
            #pragma unroll
            for (int sp = 0; sp < NSPLIT; sp++)
                hci += hc_part[((size_t)(sp * N_GRAPHS + g) * 16 + t) * 64 + i];
            acc += hci * Wt[i * 64 + lane];
        }
        s = acc;
        if (mode == 2) {
            float xm = ab[lane] * xsum[g * 64 + lane] / fmaxf(cnt, 1.0f) + ab[64 + lane];
            s += xm;
        }
    }
    float sq = waveReduceSum(s * s);
    float scale = (sq / (1.0f + sq)) / sqrtf(sq + 1e-16f);
    float v = scale * s;
    if (mode == 2) {
        float tot = waveReduceSum(1.0f / fabsf(v));
        if (lane == 0) out[wid] = 1.0f / tot;
    } else {
        __shared__ float vlds[4][64];
        int w = threadIdx.x >> 6;
        vlds[w][lane] = v;
        __syncthreads();
        const float* WTt = WT + t * 4096;
        float acc = 0.0f;
        for (int o = 0; o < 64; o++) acc += WTt[o * 64 + lane] * vlds[w][o];
        wv[(size_t)wid * 64 + lane] = acc;
        float b = waveReduceSum(bias[t * 64 + lane] * v);
        if (lane == 0) bv[wid] = b;
    }
}

extern "C" void kernel_launch(void* const* d_in, const int* in_sizes, int n_in,
                              void* d_out, int out_size, void* d_ws, size_t ws_size,
                              hipStream_t stream) {
    const float* x     = (const float*)d_in[0];
    const int*   ei    = (const int*)d_in[1];
    const float* ew    = (const float*)d_in[2];
    const int*   batch = (const int*)d_in[3];
    const float* gamma = (const float*)d_in[4];
    const float* beta  = (const float*)d_in[5];
    const float* W     = (const float*)d_in[6];
    const float* bias  = (const float*)d_in[7];
    float* out = (float*)d_out;

    const int* row = ei;
    const int* col = ei + N_EDGES;

    char* basep = (char*)d_ws;
    int2* rec = (int2*)basep;                              basep += sizeof(int2) * N_EDGES;
    unsigned long long* pack = (unsigned long long*)basep; basep += 8ULL * NPART * N_NODES;
    __half2* x16 = (__half2*)basep;                        basep += 2ULL * N_NODES * D_CH;
    float* p = (float*)basep;
    float* h        = p; p += (size_t)N_NODES * D_CH;
    float* hc_part  = p; p += (size_t)NSPLIT * N_GRAPHS * T_CAPS * D_CH;
    float* csum_part= p; p += NSPLIT * N_GRAPHS * T_CAPS;
    float* wva      = p; p += N_GRAPHS * T_CAPS * D_CH;
    float* bva      = p; p += N_GRAPHS * T_CAPS;
    float* wvb      = p; p += N_GRAPHS * T_CAPS * D_CH;
    float* bvb      = p; p += N_GRAPHS * T_CAPS;
    float* WT       = p; p += T_CAPS * 64 * 64;
    float* dinv     = p; p += N_NODES;
    float* bn_sums  = p; p += 128;
    float* ab       = p; p += 128;
    float* hsum     = p; p += N_GRAPHS * D_CH;
    float* xsum     = p; p += N_GRAPHS * D_CH;
    int*   ip       = (int*)p;
    int*   off      = ip; ip += N_NODES + 1;
    int*   rank     = ip; ip += N_EDGES;
    int*   poff     = ip; ip += NPART * N_NODES;
    int*   bsum     = ip; ip += 128;
    int*   gstart   = ip; ip += N_GRAPHS + 1;

    const int nscan = (N_NODES + 1023) / 1024;

    setup_kernel<<<(NPART * N_NODES + 255) / 256, 256, 0, stream>>>(pack, bn_sums, hsum, xsum,
                                                                     W, WT, batch, gstart);
    histbn_kernel<<<HIST_BLOCKS + NBN, 256, 0, stream>>>(col, ew, pack, rank, x, bn_sums, x16);
    scan1_kernel<<<nscan, 256, 0, stream>>>(pack, off, bsum, poff, dinv, bn_sums, gamma, beta, ab);
    scan2_kernel<<<1, 128, 0, stream>>>(bsum, nscan);
    scan3_kernel<<<(N_NODES + 255) / 256, 256, 0, stream>>>(off, bsum, poff);
    scatter_kernel<<<(N_EDGES + 255) / 256, 256, 0, stream>>>(row, col, ew, rank, dinv, poff, rec);
    h_gather_kernel<<<N_NODES / 4, 256, 0, stream>>>(rec, off, dinv, (const __half*)x16, ab, h);
    gsum_kernel<<<N_GRAPHS * NSPLIT, 256, 0, stream>>>((const __half*)x16, h, gstart, xsum, hsum);

    kb_kernel<<<N_GRAPHS * T_CAPS / 4, 256, 0, stream>>>(hsum, hc_part, csum_part, W, WT, bias,
                                                          xsum, ab, gstart, wva, bva, out, 0);
    ka_fused_kernel<<<N_GRAPHS * NSPLIT, 256, 0, stream>>>(h, gstart, wva, bva, wvb, bvb,
                                                            hc_part, csum_part, 0);
    kb_kernel<<<N_GRAPHS * T_CAPS / 4, 256, 0, stream>>>(hsum, hc_part, csum_part, W, WT, bias,
                                                          xsum, ab, gstart, wvb, bvb, out, 1);
    ka_fused_kernel<<<N_GRAPHS * NSPLIT, 256, 0, stream>>>(h, gstart, wva, bva, wvb, bvb,
                                                            hc_part, csum_part, 1);
    kb_kernel<<<N_GRAPHS * T_CAPS / 4, 256, 0, stream>>>(hsum, hc_part, csum_part, W, WT, bias,
                                                          xsum, ab, gstart, wva, bva, out, 2);
}

// Round 9
// 279.047 us; speedup vs baseline: 1.2622x; 1.2043x over previous
//
#include <hip/hip_runtime.h>
#include <hip/hip_fp16.h>
#include <math.h>

#define N_NODES 100000
#define N_EDGES 1600000
#define N_GRAPHS 256
#define T_CAPS 16
#define D_CH 64
#define BN_EPS 1e-5f
#define NSPLIT 8
#define CHUNK 32
#define FIX_SCALE 33554432.0f   // 2^25
#define NB 782                  // ceil(N_NODES/128) buckets of 128 cols
#define EPB 4096                // edges per block in pass A/C
#define NBLK 391                // ceil(N_EDGES/EPB)
#define NBN 512                 // BN blocks fused into pass A

__device__ __forceinline__ float waveReduceSum(float v) {
    for (int m = 32; m >= 1; m >>= 1) v += __shfl_xor(v, m, 64);
    return v;
}

// ---- setup: zero bn_sums/hsum/xsum, WT transpose, gstart binary search ----
__global__ void setup_kernel(float* bn_sums, float* hsum, float* xsum,
                             const float* __restrict__ W, float* __restrict__ WT,
                             const int* __restrict__ batch, int* __restrict__ gstart) {
    int idx = blockIdx.x * blockDim.x + threadIdx.x;
    if (idx < 128) bn_sums[idx] = 0.0f;
    if (idx < N_GRAPHS * D_CH) { hsum[idx] = 0.0f; xsum[idx] = 0.0f; }
    if (idx < T_CAPS * 64 * 64) {
        int t = idx >> 12, rem = idx & 4095, o = rem >> 6, i = rem & 63;
        WT[idx] = W[t * 4096 + i * 64 + o];
    }
    if (idx <= N_GRAPHS) {
        int lo = 0, hi = N_NODES;
        while (lo < hi) { int mid = (lo + hi) >> 1; if (batch[mid] < idx) lo = mid + 1; else hi = mid; }
        gstart[idx] = lo;
    }
}

// ---- pass A (blocks < NBLK): LDS bucket histogram -> gh[blk][b].
//      blocks >= NBLK: BN stats + fp16 staging ----
__global__ void passA_bn_kernel(const int* __restrict__ col, int* __restrict__ gh,
                                const float* __restrict__ x, float* __restrict__ sums,
                                __half2* __restrict__ x16) {
    int blk = blockIdx.x;
    int tid = threadIdx.x;
    if (blk < NBLK) {
        __shared__ unsigned hist[NB];
        for (int j = tid; j < NB; j += 256) hist[j] = 0u;
        __syncthreads();
        #pragma unroll
        for (int i = 0; i < EPB / 256; i++) {
            int e = blk * EPB + i * 256 + tid;
            if (e < N_EDGES) atomicAdd(&hist[col[e] >> 7], 1u);
        }
        __syncthreads();
        for (int j = tid; j < NB; j += 256) gh[blk * NB + j] = (int)hist[j];
    } else {
        int bb = blk - NBLK;
        int pr = tid & 31;
        int rg = tid >> 5;
        int c0 = pr * 2;
        float s0 = 0, q0 = 0, s1 = 0, q1 = 0;
        for (int r = bb * 8 + rg; r < N_NODES; r += NBN * 8) {
            float2 v = *(const float2*)(x + (size_t)r * 64 + c0);
            s0 += v.x; q0 += v.x * v.x;
            s1 += v.y; q1 += v.y * v.y;
            x16[(size_t)r * 32 + pr] = __floats2half2_rn(v.x, v.y);
        }
        __shared__ float ls[2][8][64];
        ls[0][rg][c0] = s0; ls[0][rg][c0 + 1] = s1;
        ls[1][rg][c0] = q0; ls[1][rg][c0 + 1] = q1;
        __syncthreads();
        if (tid < 64) {
            float a = 0.0f, bsm = 0.0f;
            for (int i = 0; i < 8; i++) { a += ls[0][i][tid]; bsm += ls[1][i][tid]; }
            atomicAdd(&sums[tid], a);
            atomicAdd(&sums[64 + tid], bsm);
        }
    }
}

// ---- pass B1: per-bucket exclusive scan over blocks (in-place in gh) + totals ----
__global__ void passB1_kernel(int* __restrict__ gh, int* __restrict__ Tarr) {
    int b = blockIdx.x;
    int tid = threadIdx.x;
    __shared__ int lds[256];
    int i0 = tid * 2, i1 = tid * 2 + 1;
    int v0 = (i0 < NBLK) ? gh[(size_t)i0 * NB + b] : 0;
    int v1 = (i1 < NBLK) ? gh[(size_t)i1 * NB + b] : 0;
    int pair = v0 + v1;
    lds[tid] = pair;
    __syncthreads();
    for (int d = 1; d < 256; d <<= 1) {
        int v = (tid >= d) ? lds[tid - d] : 0;
        __syncthreads();
        lds[tid] += v;
        __syncthreads();
    }
    int excl = lds[tid] - pair;
    if (i0 < NBLK) gh[(size_t)i0 * NB + b] = excl;
    if (i1 < NBLK) gh[(size_t)i1 * NB + b] = excl + v0;
    if (tid == 255) Tarr[b] = lds[255];
}

// ---- pass B2: exclusive scan of bucket totals -> Sarr; Sarr[NB]=E; off[N]=E ----
__global__ void passB2_kernel(const int* __restrict__ Tarr, int* __restrict__ Sarr,
                              int* __restrict__ off) {
    __shared__ int lds[256];
    int tid = threadIdx.x;
    int base = tid * 4;
    int t0 = (base + 0 < NB) ? Tarr[base + 0] : 0;
    int t1 = (base + 1 < NB) ? Tarr[base + 1] : 0;
    int t2 = (base + 2 < NB) ? Tarr[base + 2] : 0;
    int t3 = (base + 3 < NB) ? Tarr[base + 3] : 0;
    int tsum = t0 + t1 + t2 + t3;
    lds[tid] = tsum;
    __syncthreads();
    for (int d = 1; d < 256; d <<= 1) {
        int v = (tid >= d) ? lds[tid - d] : 0;
        __syncthreads();
        lds[tid] += v;
        __syncthreads();
    }
    int excl = lds[tid] - tsum;
    if (base + 0 < NB) Sarr[base + 0] = excl;
    if (base + 1 < NB) Sarr[base + 1] = excl + t0;
    if (base + 2 < NB) Sarr[base + 2] = excl + t0 + t1;
    if (base + 3 < NB) Sarr[base + 3] = excl + t0 + t1 + t2;
    if (tid == 0) { Sarr[NB] = N_EDGES; off[N_NODES] = N_EDGES; }
}

// ---- pass C: bucket-group edges. brec[pos] = (colLow<<17 | row, ew bits) ----
__global__ void passC_kernel(const int* __restrict__ row, const int* __restrict__ col,
                             const float* __restrict__ ew, const int* __restrict__ gh,
                             const int* __restrict__ Sarr, int2* __restrict__ brec) {
    int blk = blockIdx.x;
    int tid = threadIdx.x;
    __shared__ int cur[NB];
    for (int j = tid; j < NB; j += 256) cur[j] = Sarr[j] + gh[(size_t)blk * NB + j];
    __syncthreads();
    #pragma unroll
    for (int i = 0; i < EPB / 256; i++) {
        int e = blk * EPB + i * 256 + tid;
        if (e < N_EDGES) {
            int c = col[e], r = row[e];
            float w = ew[e];
            int b = c >> 7;
            int pos = atomicAdd(&cur[b], 1);
            brec[pos] = make_int2(((c & 127) << 17) | r, __float_as_int(w));
        }
    }
}

// ---- pass D: per-bucket counting sort by col&127; degree (fixed-point, deterministic);
//      emits dinv, off, col-sorted rec=(row, ew bits) ----
__global__ void passD_kernel(const int2* __restrict__ brec, const int* __restrict__ Sarr,
                             float* __restrict__ dinv, int* __restrict__ off,
                             int2* __restrict__ rec) {
    int b = blockIdx.x;
    int tid = threadIdx.x;
    int s0 = Sarr[b], s1 = Sarr[b + 1];
    __shared__ unsigned cnt[128];
    __shared__ unsigned degfx[128];
    __shared__ int scan_tmp[128];
    __shared__ int cOff[128];
    __shared__ int cursor[128];
    if (tid < 128) { cnt[tid] = 0u; degfx[tid] = 0u; }
    __syncthreads();
    for (int e = s0 + tid; e < s1; e += 256) {
        int2 rc = brec[e];
        int cl = (rc.x >> 17) & 127;
        atomicAdd(&cnt[cl], 1u);
        unsigned fx = __float2uint_rn(__int_as_float(rc.y) * FIX_SCALE);
        atomicAdd(&degfx[cl], fx);
    }
    __syncthreads();
    if (tid < 128) scan_tmp[tid] = (int)cnt[tid];
    __syncthreads();
    for (int d = 1; d < 128; d <<= 1) {
        int v = 0;
        if (tid < 128 && tid >= d) v = scan_tmp[tid - d];
        __syncthreads();
        if (tid < 128) scan_tmp[tid] += v;
        __syncthreads();
    }
    if (tid < 128) {
        int excl = scan_tmp[tid] - (int)cnt[tid];
        cOff[tid] = excl;
        cursor[tid] = excl;
        int cg = b * 128 + tid;
        if (cg < N_NODES) {
            float d = 1.0f + (float)degfx[tid] * (1.0f / FIX_SCALE);
            dinv[cg] = 1.0f / sqrtf(d);
            off[cg] = s0 + excl;
        }
    }
    __syncthreads();
    for (int e = s0 + tid; e < s1; e += 256) {
        int2 rc = brec[e];
        int cl = (rc.x >> 17) & 127;
        int pos = atomicAdd((unsigned*)&cursor[cl], 1u);
        rec[s0 + (int)pos] = make_int2(rc.x & 0x1FFFF, rc.y);
    }
}

// ---- gather (fp16 x): h = a*(sum coef*x) + b*(sum coef); coef from dinv[row]*ew*dinv[n] ----
__global__ void h_gather_kernel(const int2* __restrict__ rec, const int* __restrict__ off,
                                const float* __restrict__ dinv, const __half* __restrict__ x16,
                                const float* __restrict__ ab, float* __restrict__ h) {
    int n = blockIdx.x * 4 + (threadIdx.x >> 6);
    int ch = threadIdx.x & 63;
    int e0 = off[n], e1 = off[n + 1];
    float dv = dinv[n];
    float cself = dv * dv;
    float acc0 = cself * __half2float(x16[(size_t)n * 64 + ch]);
    float acc1 = 0.0f, acc2 = 0.0f, acc3 = 0.0f;
    float csr = cself;
    int e = e0;
    for (; e + 4 <= e1; e += 4) {
        int2 r0 = rec[e], r1 = rec[e + 1], r2 = rec[e + 2], r3 = rec[e + 3];
        float c0 = dinv[r0.x] * __int_as_float(r0.y) * dv;
        float c1 = dinv[r1.x] * __int_as_float(r1.y) * dv;
        float c2 = dinv[r2.x] * __int_as_float(r2.y) * dv;
        float c3 = dinv[r3.x] * __int_as_float(r3.y) * dv;
        float x0 = __half2float(x16[(size_t)r0.x * 64 + ch]);
        float x1 = __half2float(x16[(size_t)r1.x * 64 + ch]);
        float x2 = __half2float(x16[(size_t)r2.x * 64 + ch]);
        float x3 = __half2float(x16[(size_t)r3.x * 64 + ch]);
        acc0 += c0 * x0; acc1 += c1 * x1; acc2 += c2 * x2; acc3 += c3 * x3;
        csr += c0 + c1 + c2 + c3;
    }
    for (; e < e1; ++e) {
        int2 rc = rec[e];
        float c = dinv[rc.x] * __int_as_float(rc.y) * dv;
        acc0 += c * __half2float(x16[(size_t)rc.x * 64 + ch]);
        csr += c;
    }
    float acc = (acc0 + acc1) + (acc2 + acc3);
    h[(size_t)n * 64 + ch] = ab[ch] * acc + ab[64 + ch] * csr;
}

// ---- BN affine from sums (tiny) ----
__global__ void ab_kernel(const float* __restrict__ sums, const float* __restrict__ gamma,
                          const float* __restrict__ beta, float* __restrict__ ab) {
    int tid = threadIdx.x;
    if (tid < 64) {
        float mu = sums[tid] * (1.0f / N_NODES);
        float var = sums[64 + tid] * (1.0f / N_NODES) - mu * mu;
        float inv = 1.0f / sqrtf(var + BN_EPS);
        float a = inv * gamma[tid];
        ab[tid] = a;
        ab[64 + tid] = beta[tid] - mu * a;
    }
}

// ---- per-graph sums of x16 and of h (atomic partials) ----
__global__ void gsum_kernel(const __half* __restrict__ x16, const float* __restrict__ h,
                            const int* __restrict__ gstart, float* __restrict__ xsum,
                            float* __restrict__ hsum) {
    int g = blockIdx.x / NSPLIT, sp = blockIdx.x % NSPLIT;
    int s0g = gstart[g], s1g = gstart[g + 1];
    int len = s1g - s0g;
    int q = (len + NSPLIT - 1) / NSPLIT;
    int a0 = s0g + sp * q, a1 = min(s1g, a0 + q);
    int ch = threadIdx.x & 63, rg = threadIdx.x >> 6;
    float ax = 0.0f, ah = 0.0f;
    for (int n = a0 + rg; n < a1; n += 4) {
        ax += __half2float(x16[(size_t)n * 64 + ch]);
        ah += h[(size_t)n * 64 + ch];
    }
    __shared__ float lx[4][64], lh[4][64];
    lx[rg][ch] = ax; lh[rg][ch] = ah;
    __syncthreads();
    if (threadIdx.x < 64) {
        int c = threadIdx.x;
        float sx = lx[0][c] + lx[1][c] + lx[2][c] + lx[3][c];
        float sh = lh[0][c] + lh[1][c] + lh[2][c] + lh[3][c];
        atomicAdd(&xsum[g * 64 + c], sx);
        atomicAdd(&hsum[g * 64 + c], sh);
    }
}

// ---- fused routing: thread-parallel logit dot + in-register softmax + accumulate ----
__global__ void ka_fused_kernel(const float* __restrict__ h, const int* __restrict__ gstart,
                                const float* __restrict__ wva, const float* __restrict__ bva,
                                const float* __restrict__ wvb, const float* __restrict__ bvb,
                                float* __restrict__ hc_part, float* __restrict__ csum_part,
                                int mode) {
    int g = blockIdx.x / NSPLIT, sp = blockIdx.x % NSPLIT;
    int s0g = gstart[g], s1g = gstart[g + 1];
    int len = s1g - s0g;
    int q = (len + NSPLIT - 1) / NSPLIT;
    int s0 = s0g + sp * q, s1 = min(s1g, s0 + q);
    int tid = threadIdx.x;
    int d = tid & 63, tg = tid >> 6;
    int t = tid & 15, kh = tid >> 4;

    __shared__ float hlds[CHUNK][65];
    __shared__ float wa[16][65];
    __shared__ float wb[16][65];
    __shared__ float clds[CHUNK][17];
    __shared__ float bvl[2][16];

    for (int i = tid; i < 16 * 64; i += 256) {
        int tt = i >> 6, dd = i & 63;
        wa[tt][dd] = wva[(g * 16 + tt) * 64 + dd];
        if (mode) wb[tt][dd] = wvb[(g * 16 + tt) * 64 + dd];
    }
    if (tid < 16) { bvl[0][tid] = bva[g * 16 + tid]; bvl[1][tid] = mode ? bvb[g * 16 + tid] : 0.0f; }
    for (int i = tid; i < CHUNK * 65; i += 256) ((float*)hlds)[i] = 0.0f;
    __syncthreads();

    float acc0 = 0, acc1 = 0, acc2 = 0, acc3 = 0;
    float cs0 = 0, cs1 = 0, cs2 = 0, cs3 = 0;

    for (int n0 = s0; n0 < s1; n0 += CHUNK) {
        int nn = min(CHUNK, s1 - n0);
        #pragma unroll
        for (int j = 0; j < 8; j++) {
            int k = tg * 8 + j;
            if (k < nn) hlds[k][d] = h[(size_t)(n0 + k) * 64 + d];
        }
        __syncthreads();
        int k0 = kh, k1 = kh + 16;
        float u0, u1;
        if (mode) {
            float a0 = bvl[0][t], a1 = bvl[0][t], b0 = bvl[1][t], b1 = bvl[1][t];
            for (int dd = 0; dd < 64; dd++) {
                float wav = wa[t][dd], wbv = wb[t][dd];
                float h0 = hlds[k0][dd], h1 = hlds[k1][dd];
                a0 += h0 * wav; a1 += h1 * wav;
                b0 += h0 * wbv; b1 += h1 * wbv;
            }
            u0 = a0 + b0; u1 = a1 + b1;
        } else {
            float a0 = bvl[0][t], a1 = bvl[0][t];
            for (int dd = 0; dd < 64; dd++) {
                float wav = wa[t][dd];
                a0 += hlds[k0][dd] * wav; a1 += hlds[k1][dd] * wav;
            }
            u0 = a0; u1 = a1;
        }
        float m0 = u0, m1 = u1;
        #pragma unroll
        for (int msk = 1; msk < 16; msk <<= 1) {
            m0 = fmaxf(m0, __shfl_xor(m0, msk, 64));
            m1 = fmaxf(m1, __shfl_xor(m1, msk, 64));
        }
        float e0 = expf(u0 - m0), e1 = expf(u1 - m1);
        float z0 = e0, z1 = e1;
        #pragma unroll
        for (int msk = 1; msk < 16; msk <<= 1) {
            z0 += __shfl_xor(z0, msk, 64);
            z1 += __shfl_xor(z1, msk, 64);
        }
        if (k0 < nn) clds[k0][t] = e0 / z0;
        if (k1 < nn) clds[k1][t] = e1 / z1;
        __syncthreads();
        for (int k = 0; k < nn; k++) {
            float hv = hlds[k][d];
            float c0 = clds[k][tg * 4 + 0], c1 = clds[k][tg * 4 + 1];
            float c2 = clds[k][tg * 4 + 2], c3 = clds[k][tg * 4 + 3];
            acc0 += c0 * hv; acc1 += c1 * hv; acc2 += c2 * hv; acc3 += c3 * hv;
            if (d == 0) { cs0 += c0; cs1 += c1; cs2 += c2; cs3 += c3; }
        }
        __syncthreads();
    }
    size_t base = ((size_t)(sp * N_GRAPHS + g) * 16 + tg * 4) * 64 + d;
    hc_part[base] = acc0; hc_part[base + 64] = acc1;
    hc_part[base + 128] = acc2; hc_part[base + 192] = acc3;
    if (d == 0) {
        int cb = (sp * N_GRAPHS + g) * 16 + tg * 4;
        csum_part[cb + 0] = cs0; csum_part[cb + 1] = cs1;
        csum_part[cb + 2] = cs2; csum_part[cb + 3] = cs3;
    }
}

// ---- kb: one wave per (g,t). mode 0: uniform-softmax path; 1: mid; 2: final+out ----
__global__ void kb_kernel(const float* __restrict__ hsum, const float* __restrict__ hc_part,
                          const float* __restrict__ csum_part, const float* __restrict__ W,
                          const float* __restrict__ WT, const float* __restrict__ bias,
                          const float* __restrict__ xsum, const float* __restrict__ ab,
                          const int* __restrict__ gstart, float* __restrict__ wv,
                          float* __restrict__ bv, float* __restrict__ out, int mode) {
    int wid = blockIdx.x * 4 + (threadIdx.x >> 6);
    int lane = threadIdx.x & 63;
    int g = wid >> 4, t = wid & 15;
    const float* Wt = W + t * 4096;
    float cnt = (float)(gstart[g + 1] - gstart[g]);
    float s;
    if (mode == 0) {
        const float* hr = hsum + g * 64;
        float acc = cnt * bias[t * 64 + lane];
        for (int i = 0; i < 64; i++) acc += hr[i] * Wt[i * 64 + lane];
        s = acc * (1.0f / 16.0f);
    } else {
        float csum = 0.0f;
        #pragma unroll
        for (int sp = 0; sp < NSPLIT; sp++) csum += csum_part[(sp * N_GRAPHS + g) * 16 + t];
        float acc = csum * bias[t * 64 + lane];
        for (int i = 0; i < 64; i++) {
            float hci = 0.0f;
            #pragma unroll
            for (int sp = 0; sp < NSPLIT; sp++)
                hci += hc_part[((size_t)(sp * N_GRAPHS + g) * 16 + t) * 64 + i];
            acc += hci * Wt[i * 64 + lane];
        }
        s = acc;
        if (mode == 2) {
            float xm = ab[lane] * xsum[g * 64 + lane] / fmaxf(cnt, 1.0f) + ab[64 + lane];
            s += xm;
        }
    }
    float sq = waveReduceSum(s * s);
    float scale = (sq / (1.0f + sq)) / sqrtf(sq + 1e-16f);
    float v = scale * s;
    if (mode == 2) {
        float tot = waveReduceSum(1.0f / fabsf(v));
        if (lane == 0) out[wid] = 1.0f / tot;
    } else {
        __shared__ float vlds[4][64];
        int w = threadIdx.x >> 6;
        vlds[w][lane] = v;
        __syncthreads();
        const float* WTt = WT + t * 4096;
        float acc = 0.0f;
        for (int o = 0; o < 64; o++) acc += WTt[o * 64 + lane] * vlds[w][o];
        wv[(size_t)wid * 64 + lane] = acc;
        float b = waveReduceSum(bias[t * 64 + lane] * v);
        if (lane == 0) bv[wid] = b;
    }
}

extern "C" void kernel_launch(void* const* d_in, const int* in_sizes, int n_in,
                              void* d_out, int out_size, void* d_ws, size_t ws_size,
                              hipStream_t stream) {
    const float* x     = (const float*)d_in[0];
    const int*   ei    = (const int*)d_in[1];
    const float* ew    = (const float*)d_in[2];
    const int*   batch = (const int*)d_in[3];
    const float* gamma = (const float*)d_in[4];
    const float* beta  = (const float*)d_in[5];
    const float* W     = (const float*)d_in[6];
    const float* bias  = (const float*)d_in[7];
    float* out = (float*)d_out;

    const int* row = ei;
    const int* col = ei + N_EDGES;

    char* basep = (char*)d_ws;
    int2* rec  = (int2*)basep;                     basep += sizeof(int2) * N_EDGES;
    int2* brec = (int2*)basep;                     basep += sizeof(int2) * N_EDGES;
    __half2* x16 = (__half2*)basep;                basep += 2ULL * N_NODES * D_CH;
    float* p = (float*)basep;
    float* h        = p; p += (size_t)N_NODES * D_CH;
    float* hc_part  = p; p += (size_t)NSPLIT * N_GRAPHS * T_CAPS * D_CH;
    float* csum_part= p; p += NSPLIT * N_GRAPHS * T_CAPS;
    float* wva      = p; p += N_GRAPHS * T_CAPS * D_CH;
    float* bva      = p; p += N_GRAPHS * T_CAPS;
    float* wvb      = p; p += N_GRAPHS * T_CAPS * D_CH;
    float* bvb      = p; p += N_GRAPHS * T_CAPS;
    float* WT       = p; p += T_CAPS * 64 * 64;
    float* dinv     = p; p += N_NODES;
    float* bn_sums  = p; p += 128;
    float* ab       = p; p += 128;
    float* hsum     = p; p += N_GRAPHS * D_CH;
    float* xsum     = p; p += N_GRAPHS * D_CH;
    int*   ip       = (int*)p;
    int*   off      = ip; ip += N_NODES + 1;
    int*   gh       = ip; ip += (size_t)NBLK * NB;
    int*   Tarr     = ip; ip += NB;
    int*   Sarr     = ip; ip += NB + 1;
    int*   gstart   = ip; ip += N_GRAPHS + 1;

    setup_kernel<<<(T_CAPS * 64 * 64 + 255) / 256, 256, 0, stream>>>(bn_sums, hsum, xsum,
                                                                      W, WT, batch, gstart);
    passA_bn_kernel<<<NBLK + NBN, 256, 0, stream>>>(col, gh, x, bn_sums, x16);
    ab_kernel<<<1, 64, 0, stream>>>(bn_sums, gamma, beta, ab);
    passB1_kernel<<<NB, 256, 0, stream>>>(gh, Tarr);
    passB2_kernel<<<1, 256, 0, stream>>>(Tarr, Sarr, off);
    passC_kernel<<<NBLK, 256, 0, stream>>>(row, col, ew, gh, Sarr, brec);
    passD_kernel<<<NB, 256, 0, stream>>>(brec, Sarr, dinv, off, rec);
    h_gather_kernel<<<N_NODES / 4, 256, 0, stream>>>(rec, off, dinv, (const __half*)x16, ab, h);
    gsum_kernel<<<N_GRAPHS * NSPLIT, 256, 0, stream>>>((const __half*)x16, h, gstart, xsum, hsum);

    kb_kernel<<<N_GRAPHS * T_CAPS / 4, 256, 0, stream>>>(hsum, hc_part, csum_part, W, WT, bias,
                                                          xsum, ab, gstart, wva, bva, out, 0);
    ka_fused_kernel<<<N_GRAPHS * NSPLIT, 256, 0, stream>>>(h, gstart, wva, bva, wvb, bvb,
                                                            hc_part, csum_part, 0);
    kb_kernel<<<N_GRAPHS * T_CAPS / 4, 256, 0, stream>>>(hsum, hc_part, csum_part, W, WT, bias,
                                                          xsum, ab, gstart, wvb, bvb, out, 1);
    ka_fused_kernel<<<N_GRAPHS * NSPLIT, 256, 0, stream>>>(h, gstart, wva, bva, wvb, bvb,
                                                            hc_part, csum_part, 1);
    kb_kernel<<<N_GRAPHS * T_CAPS / 4, 256, 0, stream>>>(hsum, hc_part, csum_part, W, WT, bias,
                                                          xsum, ab, gstart, wva, bva, out, 2);
}

// Round 10
// 274.861 us; speedup vs baseline: 1.2814x; 1.0152x over previous
//
#include <hip/hip_runtime.h>
#include <hip/hip_fp16.h>
#include <math.h>

#define N_NODES 100000
#define N_EDGES 1600000
#define N_GRAPHS 256
#define T_CAPS 16
#define D_CH 64
#define BN_EPS 1e-5f
#define NSPLIT 8
#define CHUNK 32
#define FIX_SCALE 33554432.0f   // 2^25
#define NB 782                  // ceil(N_NODES/128) buckets of 128 cols
#define EPB 4096                // edges per block in pass A/C
#define NBLK 391                // ceil(N_EDGES/EPB)
#define NBN 512                 // BN blocks fused into pass A

__device__ __forceinline__ float waveReduceSum(float v) {
    for (int m = 32; m >= 1; m >>= 1) v += __shfl_xor(v, m, 64);
    return v;
}

// ---- setup: zero bn_sums/hsum/xsum, WT transpose, gstart binary search ----
__global__ void setup_kernel(float* bn_sums, float* hsum, float* xsum,
                             const float* __restrict__ W, float* __restrict__ WT,
                             const int* __restrict__ batch, int* __restrict__ gstart) {
    int idx = blockIdx.x * blockDim.x + threadIdx.x;
    if (idx < 128) bn_sums[idx] = 0.0f;
    if (idx < N_GRAPHS * D_CH) { hsum[idx] = 0.0f; xsum[idx] = 0.0f; }
    if (idx < T_CAPS * 64 * 64) {
        int t = idx >> 12, rem = idx & 4095, o = rem >> 6, i = rem & 63;
        WT[idx] = W[t * 4096 + i * 64 + o];
    }
    if (idx <= N_GRAPHS) {
        int lo = 0, hi = N_NODES;
        while (lo < hi) { int mid = (lo + hi) >> 1; if (batch[mid] < idx) lo = mid + 1; else hi = mid; }
        gstart[idx] = lo;
    }
}

// ---- pass A (blocks < NBLK): LDS bucket histogram -> gh[blk][b].
//      blocks >= NBLK: BN stats + fp16 staging ----
__global__ void passA_bn_kernel(const int* __restrict__ col, int* __restrict__ gh,
                                const float* __restrict__ x, float* __restrict__ sums,
                                __half2* __restrict__ x16) {
    int blk = blockIdx.x;
    int tid = threadIdx.x;
    if (blk < NBLK) {
        __shared__ unsigned hist[NB];
        for (int j = tid; j < NB; j += 256) hist[j] = 0u;
        __syncthreads();
        #pragma unroll
        for (int i = 0; i < EPB / 256; i++) {
            int e = blk * EPB + i * 256 + tid;
            if (e < N_EDGES) atomicAdd(&hist[col[e] >> 7], 1u);
        }
        __syncthreads();
        for (int j = tid; j < NB; j += 256) gh[blk * NB + j] = (int)hist[j];
    } else {
        int bb = blk - NBLK;
        int pr = tid & 31;
        int rg = tid >> 5;
        int c0 = pr * 2;
        float s0 = 0, q0 = 0, s1 = 0, q1 = 0;
        for (int r = bb * 8 + rg; r < N_NODES; r += NBN * 8) {
            float2 v = *(const float2*)(x + (size_t)r * 64 + c0);
            s0 += v.x; q0 += v.x * v.x;
            s1 += v.y; q1 += v.y * v.y;
            x16[(size_t)r * 32 + pr] = __floats2half2_rn(v.x, v.y);
        }
        __shared__ float ls[2][8][64];
        ls[0][rg][c0] = s0; ls[0][rg][c0 + 1] = s1;
        ls[1][rg][c0] = q0; ls[1][rg][c0 + 1] = q1;
        __syncthreads();
        if (tid < 64) {
            float a = 0.0f, bsm = 0.0f;
            for (int i = 0; i < 8; i++) { a += ls[0][i][tid]; bsm += ls[1][i][tid]; }
            atomicAdd(&sums[tid], a);
            atomicAdd(&sums[64 + tid], bsm);
        }
    }
}

// ---- pass B1: per-bucket exclusive scan over blocks (in-place in gh) + totals ----
__global__ void passB1_kernel(int* __restrict__ gh, int* __restrict__ Tarr) {
    int b = blockIdx.x;
    int tid = threadIdx.x;
    __shared__ int lds[256];
    int i0 = tid * 2, i1 = tid * 2 + 1;
    int v0 = (i0 < NBLK) ? gh[(size_t)i0 * NB + b] : 0;
    int v1 = (i1 < NBLK) ? gh[(size_t)i1 * NB + b] : 0;
    int pair = v0 + v1;
    lds[tid] = pair;
    __syncthreads();
    for (int d = 1; d < 256; d <<= 1) {
        int v = (tid >= d) ? lds[tid - d] : 0;
        __syncthreads();
        lds[tid] += v;
        __syncthreads();
    }
    int excl = lds[tid] - pair;
    if (i0 < NBLK) gh[(size_t)i0 * NB + b] = excl;
    if (i1 < NBLK) gh[(size_t)i1 * NB + b] = excl + v0;
    if (tid == 255) Tarr[b] = lds[255];
}

// ---- pass B2: exclusive scan of bucket totals -> Sarr; also BN affine ab ----
__global__ void passB2_kernel(const int* __restrict__ Tarr, int* __restrict__ Sarr,
                              int* __restrict__ off, const float* __restrict__ sums,
                              const float* __restrict__ gamma, const float* __restrict__ beta,
                              float* __restrict__ ab) {
    __shared__ int lds[256];
    int tid = threadIdx.x;
    if (tid < 64) {
        float mu = sums[tid] * (1.0f / N_NODES);
        float var = sums[64 + tid] * (1.0f / N_NODES) - mu * mu;
        float inv = 1.0f / sqrtf(var + BN_EPS);
        float a = inv * gamma[tid];
        ab[tid] = a;
        ab[64 + tid] = beta[tid] - mu * a;
    }
    int base = tid * 4;
    int t0 = (base + 0 < NB) ? Tarr[base + 0] : 0;
    int t1 = (base + 1 < NB) ? Tarr[base + 1] : 0;
    int t2 = (base + 2 < NB) ? Tarr[base + 2] : 0;
    int t3 = (base + 3 < NB) ? Tarr[base + 3] : 0;
    int tsum = t0 + t1 + t2 + t3;
    lds[tid] = tsum;
    __syncthreads();
    for (int d = 1; d < 256; d <<= 1) {
        int v = (tid >= d) ? lds[tid - d] : 0;
        __syncthreads();
        lds[tid] += v;
        __syncthreads();
    }
    int excl = lds[tid] - tsum;
    if (base + 0 < NB) Sarr[base + 0] = excl;
    if (base + 1 < NB) Sarr[base + 1] = excl + t0;
    if (base + 2 < NB) Sarr[base + 2] = excl + t0 + t1;
    if (base + 3 < NB) Sarr[base + 3] = excl + t0 + t1 + t2;
    if (tid == 0) { Sarr[NB] = N_EDGES; off[N_NODES] = N_EDGES; }
}

// ---- pass C: bucket-group edges. brec[pos] = (colLow<<17 | row, ew bits) ----
__global__ void passC_kernel(const int* __restrict__ row, const int* __restrict__ col,
                             const float* __restrict__ ew, const int* __restrict__ gh,
                             const int* __restrict__ Sarr, int2* __restrict__ brec) {
    int blk = blockIdx.x;
    int tid = threadIdx.x;
    __shared__ int cur[NB];
    for (int j = tid; j < NB; j += 256) cur[j] = Sarr[j] + gh[(size_t)blk * NB + j];
    __syncthreads();
    #pragma unroll
    for (int i = 0; i < EPB / 256; i++) {
        int e = blk * EPB + i * 256 + tid;
        if (e < N_EDGES) {
            int c = col[e], r = row[e];
            float w = ew[e];
            int b = c >> 7;
            int pos = atomicAdd(&cur[b], 1);
            brec[pos] = make_int2(((c & 127) << 17) | r, __float_as_int(w));
        }
    }
}

// ---- pass D: per-bucket counting sort by col&127; degree (fixed-point, deterministic);
//      emits dinv, off, col-sorted rec=(row, ew bits) ----
__global__ void passD_kernel(const int2* __restrict__ brec, const int* __restrict__ Sarr,
                             float* __restrict__ dinv, int* __restrict__ off,
                             int2* __restrict__ rec) {
    int b = blockIdx.x;
    int tid = threadIdx.x;
    int s0 = Sarr[b], s1 = Sarr[b + 1];
    __shared__ unsigned cnt[128];
    __shared__ unsigned degfx[128];
    __shared__ int scan_tmp[128];
    __shared__ int cursor[128];
    if (tid < 128) { cnt[tid] = 0u; degfx[tid] = 0u; }
    __syncthreads();
    for (int e = s0 + tid; e < s1; e += 256) {
        int2 rc = brec[e];
        int cl = (rc.x >> 17) & 127;
        atomicAdd(&cnt[cl], 1u);
        unsigned fx = __float2uint_rn(__int_as_float(rc.y) * FIX_SCALE);
        atomicAdd(&degfx[cl], fx);
    }
    __syncthreads();
    if (tid < 128) scan_tmp[tid] = (int)cnt[tid];
    __syncthreads();
    for (int d = 1; d < 128; d <<= 1) {
        int v = 0;
        if (tid < 128 && tid >= d) v = scan_tmp[tid - d];
        __syncthreads();
        if (tid < 128) scan_tmp[tid] += v;
        __syncthreads();
    }
    if (tid < 128) {
        int excl = scan_tmp[tid] - (int)cnt[tid];
        cursor[tid] = excl;
        int cg = b * 128 + tid;
        if (cg < N_NODES) {
            float d = 1.0f + (float)degfx[tid] * (1.0f / FIX_SCALE);
            dinv[cg] = 1.0f / sqrtf(d);
            off[cg] = s0 + excl;
        }
    }
    __syncthreads();
    for (int e = s0 + tid; e < s1; e += 256) {
        int2 rc = brec[e];
        int cl = (rc.x >> 17) & 127;
        int pos = atomicAdd((unsigned*)&cursor[cl], 1u);
        rec[s0 + (int)pos] = make_int2(rc.x & 0x1FFFF, rc.y);
    }
}

// ---- gather (fp16 x, fp16 h out): 8-way unrolled; coef = dinv[row]*ew*dinv[n] ----
__global__ void h_gather_kernel(const int2* __restrict__ rec, const int* __restrict__ off,
                                const float* __restrict__ dinv, const __half* __restrict__ x16,
                                const float* __restrict__ ab, __half* __restrict__ h16) {
    int n = blockIdx.x * 4 + (threadIdx.x >> 6);
    int ch = threadIdx.x & 63;
    int e0 = off[n], e1 = off[n + 1];
    float dv = dinv[n];
    float cself = dv * dv;
    float acc0 = cself * __half2float(x16[(size_t)n * 64 + ch]);
    float acc1 = 0.0f, acc2 = 0.0f, acc3 = 0.0f;
    float csr = cself;
    int e = e0;
    for (; e + 8 <= e1; e += 8) {
        int2 r[8];
        #pragma unroll
        for (int i = 0; i < 8; i++) r[i] = rec[e + i];
        float cf[8], xv[8];
        #pragma unroll
        for (int i = 0; i < 8; i++) {
            cf[i] = dinv[r[i].x] * __int_as_float(r[i].y) * dv;
            xv[i] = __half2float(x16[(size_t)r[i].x * 64 + ch]);
        }
        acc0 += cf[0] * xv[0]; acc1 += cf[1] * xv[1];
        acc2 += cf[2] * xv[2]; acc3 += cf[3] * xv[3];
        acc0 += cf[4] * xv[4]; acc1 += cf[5] * xv[5];
        acc2 += cf[6] * xv[6]; acc3 += cf[7] * xv[7];
        csr += ((cf[0] + cf[1]) + (cf[2] + cf[3])) + ((cf[4] + cf[5]) + (cf[6] + cf[7]));
    }
    for (; e + 4 <= e1; e += 4) {
        int2 r0 = rec[e], r1 = rec[e + 1], r2 = rec[e + 2], r3 = rec[e + 3];
        float c0 = dinv[r0.x] * __int_as_float(r0.y) * dv;
        float c1 = dinv[r1.x] * __int_as_float(r1.y) * dv;
        float c2 = dinv[r2.x] * __int_as_float(r2.y) * dv;
        float c3 = dinv[r3.x] * __int_as_float(r3.y) * dv;
        float x0 = __half2float(x16[(size_t)r0.x * 64 + ch]);
        float x1 = __half2float(x16[(size_t)r1.x * 64 + ch]);
        float x2 = __half2float(x16[(size_t)r2.x * 64 + ch]);
        float x3 = __half2float(x16[(size_t)r3.x * 64 + ch]);
        acc0 += c0 * x0; acc1 += c1 * x1; acc2 += c2 * x2; acc3 += c3 * x3;
        csr += c0 + c1 + c2 + c3;
    }
    for (; e < e1; ++e) {
        int2 rc = rec[e];
        float c = dinv[rc.x] * __int_as_float(rc.y) * dv;
        acc0 += c * __half2float(x16[(size_t)rc.x * 64 + ch]);
        csr += c;
    }
    float acc = (acc0 + acc1) + (acc2 + acc3);
    h16[(size_t)n * 64 + ch] = __float2half(ab[ch] * acc + ab[64 + ch] * csr);
}

// ---- per-graph sums of x16 and of h16 (atomic partials) ----
__global__ void gsum_kernel(const __half* __restrict__ x16, const __half* __restrict__ h16,
                            const int* __restrict__ gstart, float* __restrict__ xsum,
                            float* __restrict__ hsum) {
    int g = blockIdx.x / NSPLIT, sp = blockIdx.x % NSPLIT;
    int s0g = gstart[g], s1g = gstart[g + 1];
    int len = s1g - s0g;
    int q = (len + NSPLIT - 1) / NSPLIT;
    int a0 = s0g + sp * q, a1 = min(s1g, a0 + q);
    int ch = threadIdx.x & 63, rg = threadIdx.x >> 6;
    float ax = 0.0f, ah = 0.0f;
    for (int n = a0 + rg; n < a1; n += 4) {
        ax += __half2float(x16[(size_t)n * 64 + ch]);
        ah += __half2float(h16[(size_t)n * 64 + ch]);
    }
    __shared__ float lx[4][64], lh[4][64];
    lx[rg][ch] = ax; lh[rg][ch] = ah;
    __syncthreads();
    if (threadIdx.x < 64) {
        int c = threadIdx.x;
        float sx = lx[0][c] + lx[1][c] + lx[2][c] + lx[3][c];
        float sh = lh[0][c] + lh[1][c] + lh[2][c] + lh[3][c];
        atomicAdd(&xsum[g * 64 + c], sx);
        atomicAdd(&hsum[g * 64 + c], sh);
    }
}

// ---- fused routing: thread-parallel logit dot + in-register softmax + accumulate ----
__global__ void ka_fused_kernel(const __half* __restrict__ h16, const int* __restrict__ gstart,
                                const float* __restrict__ wva, const float* __restrict__ bva,
                                const float* __restrict__ wvb, const float* __restrict__ bvb,
                                float* __restrict__ hc_part, float* __restrict__ csum_part,
                                int mode) {
    int g = blockIdx.x / NSPLIT, sp = blockIdx.x % NSPLIT;
    int s0g = gstart[g], s1g = gstart[g + 1];
    int len = s1g - s0g;
    int q = (len + NSPLIT - 1) / NSPLIT;
    int s0 = s0g + sp * q, s1 = min(s1g, s0 + q);
    int tid = threadIdx.x;
    int d = tid & 63, tg = tid >> 6;
    int t = tid & 15, kh = tid >> 4;

    __shared__ float hlds[CHUNK][65];
    __shared__ float wa[16][65];
    __shared__ float wb[16][65];
    __shared__ float clds[CHUNK][17];
    __shared__ float bvl[2][16];

    for (int i = tid; i < 16 * 64; i += 256) {
        int tt = i >> 6, dd = i & 63;
        wa[tt][dd] = wva[(g * 16 + tt) * 64 + dd];
        if (mode) wb[tt][dd] = wvb[(g * 16 + tt) * 64 + dd];
    }
    if (tid < 16) { bvl[0][tid] = bva[g * 16 + tid]; bvl[1][tid] = mode ? bvb[g * 16 + tid] : 0.0f; }
    for (int i = tid; i < CHUNK * 65; i += 256) ((float*)hlds)[i] = 0.0f;
    __syncthreads();

    float acc0 = 0, acc1 = 0, acc2 = 0, acc3 = 0;
    float cs0 = 0, cs1 = 0, cs2 = 0, cs3 = 0;

    for (int n0 = s0; n0 < s1; n0 += CHUNK) {
        int nn = min(CHUNK, s1 - n0);
        #pragma unroll
        for (int j = 0; j < 8; j++) {
            int k = tg * 8 + j;
            if (k < nn) hlds[k][d] = __half2float(h16[(size_t)(n0 + k) * 64 + d]);
        }
        __syncthreads();
        int k0 = kh, k1 = kh + 16;
        float u0, u1;
        if (mode) {
            float a0 = bvl[0][t], a1 = bvl[0][t], b0 = bvl[1][t], b1 = bvl[1][t];
            for (int dd = 0; dd < 64; dd++) {
                float wav = wa[t][dd], wbv = wb[t][dd];
                float h0 = hlds[k0][dd], h1 = hlds[k1][dd];
                a0 += h0 * wav; a1 += h1 * wav;
                b0 += h0 * wbv; b1 += h1 * wbv;
            }
            u0 = a0 + b0; u1 = a1 + b1;
        } else {
            float a0 = bvl[0][t], a1 = bvl[0][t];
            for (int dd = 0; dd < 64; dd++) {
                float wav = wa[t][dd];
                a0 += hlds[k0][dd] * wav; a1 += hlds[k1][dd] * wav;
            }
            u0 = a0; u1 = a1;
        }
        float m0 = u0, m1 = u1;
        #pragma unroll
        for (int msk = 1; msk < 16; msk <<= 1) {
            m0 = fmaxf(m0, __shfl_xor(m0, msk, 64));
            m1 = fmaxf(m1, __shfl_xor(m1, msk, 64));
        }
        float e0 = expf(u0 - m0), e1 = expf(u1 - m1);
        float z0 = e0, z1 = e1;
        #pragma unroll
        for (int msk = 1; msk < 16; msk <<= 1) {
            z0 += __shfl_xor(z0, msk, 64);
            z1 += __shfl_xor(z1, msk, 64);
        }
        if (k0 < nn) clds[k0][t] = e0 / z0;
        if (k1 < nn) clds[k1][t] = e1 / z1;
        __syncthreads();
        for (int k = 0; k < nn; k++) {
            float hv = hlds[k][d];
            float c0 = clds[k][tg * 4 + 0], c1 = clds[k][tg * 4 + 1];
            float c2 = clds[k][tg * 4 + 2], c3 = clds[k][tg * 4 + 3];
            acc0 += c0 * hv; acc1 += c1 * hv; acc2 += c2 * hv; acc3 += c3 * hv;
            if (d == 0) { cs0 += c0; cs1 += c1; cs2 += c2; cs3 += c3; }
        }
        __syncthreads();
    }
    size_t base = ((size_t)(sp * N_GRAPHS + g) * 16 + tg * 4) * 64 + d;
    hc_part[base] = acc0; hc_part[base + 64] = acc1;
    hc_part[base + 128] = acc2; hc_part[base + 192] = acc3;
    if (d == 0) {
        int cb = (sp * N_GRAPHS + g) * 16 + tg * 4;
        csum_part[cb + 0] = cs0; csum_part[cb + 1] = cs1;
        csum_part[cb + 2] = cs2; csum_part[cb + 3] = cs3;
    }
}

// ---- kb: one wave per (g,t). mode 0: uniform-softmax path; 1: mid; 2: final+out ----
__global__ void kb_kernel(const float* __restrict__ hsum, const float* __restrict__ hc_part,
                          const float* __restrict__ csum_part, const float* __restrict__ W,
                          const float* __restrict__ WT, const float* __restrict__ bias,
                          const float* __restrict__ xsum, const float* __restrict__ ab,
                          const int* __restrict__ gstart, float* __restrict__ wv,
                          float* __restrict__ bv, float* __restrict__ out, int mode) {
    int wid = blockIdx.x * 4 + (threadIdx.x >> 6);
    int lane = threadIdx.x & 63;
    int g = wid >> 4, t = wid & 15;
    const float* Wt = W + t * 4096;
    float cnt = (float)(gstart[g + 1] - gstart[g]);
    float s;
    if (mode == 0) {
        const float* hr = hsum + g * 64;
        float acc = cnt * bias[t * 64 + lane];
        for (int i = 0; i < 64; i++) acc += hr[i] * Wt[i * 64 + lane];
        s = acc * (1.0f / 16.0f);
    } else {
        float csum = 0.0f;
        #pragma unroll
        for (int sp = 0; sp < NSPLIT; sp++) csum += csum_part[(sp * N_GRAPHS + g) * 16 + t];
        float acc = csum * bias[t * 64 + lane];
        for (int i = 0; i < 64; i++) {
            float hci = 0.0f;
            #pragma unroll
            for (int sp = 0; sp < NSPLIT; sp++)
                hci += hc_part[((size_t)(sp * N_GRAPHS + g) * 16 + t) * 64 + i];
            acc += hci * Wt[i * 64 + lane];
        }
        s = acc;
        if (mode == 2) {
            float xm = ab[lane] * xsum[g * 64 + lane] / fmaxf(cnt, 1.0f) + ab[64 + lane];
            s += xm;
        }
    }
    float sq = waveReduceSum(s * s);
    float scale = (sq / (1.0f + sq)) / sqrtf(sq + 1e-16f);
    float v = scale * s;
    if (mode == 2) {
        float tot = waveReduceSum(1.0f / fabsf(v));
        if (lane == 0) out[wid] = 1.0f / tot;
    } else {
        __shared__ float vlds[4][64];
        int w = threadIdx.x >> 6;
        vlds[w][lane] = v;
        __syncthreads();
        const float* WTt = WT + t * 4096;
        float acc = 0.0f;
        for (int o = 0; o < 64; o++) acc += WTt[o * 64 + lane] * vlds[w][o];
        wv[(size_t)wid * 64 + lane] = acc;
        float b = waveReduceSum(bias[t * 64 + lane] * v);
        if (lane == 0) bv[wid] = b;
    }
}

extern "C" void kernel_launch(void* const* d_in, const int* in_sizes, int n_in,
                              void* d_out, int out_size, void* d_ws, size_t ws_size,
                              hipStream_t stream) {
    const float* x     = (const float*)d_in[0];
    const int*   ei    = (const int*)d_in[1];
    const float* ew    = (const float*)d_in[2];
    const int*   batch = (const int*)d_in[3];
    const float* gamma = (const float*)d_in[4];
    const float* beta  = (const float*)d_in[5];
    const float* W     = (const float*)d_in[6];
    const float* bias  = (const float*)d_in[7];
    float* out = (float*)d_out;

    const int* row = ei;
    const int* col = ei + N_EDGES;

    char* basep = (char*)d_ws;
    int2* rec  = (int2*)basep;                     basep += sizeof(int2) * N_EDGES;
    int2* brec = (int2*)basep;                     basep += sizeof(int2) * N_EDGES;
    __half2* x16 = (__half2*)basep;                basep += 2ULL * N_NODES * D_CH;
    __half* h16 = (__half*)basep;                  basep += 2ULL * N_NODES * D_CH;
    float* p = (float*)basep;
    float* hc_part  = p; p += (size_t)NSPLIT * N_GRAPHS * T_CAPS * D_CH;
    float* csum_part= p; p += NSPLIT * N_GRAPHS * T_CAPS;
    float* wva      = p; p += N_GRAPHS * T_CAPS * D_CH;
    float* bva      = p; p += N_GRAPHS * T_CAPS;
    float* wvb      = p; p += N_GRAPHS * T_CAPS * D_CH;
    float* bvb      = p; p += N_GRAPHS * T_CAPS;
    float* WT       = p; p += T_CAPS * 64 * 64;
    float* dinv     = p; p += N_NODES;
    float* bn_sums  = p; p += 128;
    float* ab       = p; p += 128;
    float* hsum     = p; p += N_GRAPHS * D_CH;
    float* xsum     = p; p += N_GRAPHS * D_CH;
    int*   ip       = (int*)p;
    int*   off      = ip; ip += N_NODES + 1;
    int*   gh       = ip; ip += (size_t)NBLK * NB;
    int*   Tarr     = ip; ip += NB;
    int*   Sarr     = ip; ip += NB + 1;
    int*   gstart   = ip; ip += N_GRAPHS + 1;

    setup_kernel<<<(T_CAPS * 64 * 64 + 255) / 256, 256, 0, stream>>>(bn_sums, hsum, xsum,
                                                                      W, WT, batch, gstart);
    passA_bn_kernel<<<NBLK + NBN, 256, 0, stream>>>(col, gh, x, bn_sums, x16);
    passB1_kernel<<<NB, 256, 0, stream>>>(gh, Tarr);
    passB2_kernel<<<1, 256, 0, stream>>>(Tarr, Sarr, off, bn_sums, gamma, beta, ab);
    passC_kernel<<<NBLK, 256, 0, stream>>>(row, col, ew, gh, Sarr, brec);
    passD_kernel<<<NB, 256, 0, stream>>>(brec, Sarr, dinv, off, rec);
    h_gather_kernel<<<N_NODES / 4, 256, 0, stream>>>(rec, off, dinv, (const __half*)x16, ab, h16);
    gsum_kernel<<<N_GRAPHS * NSPLIT, 256, 0, stream>>>((const __half*)x16, h16, gstart, xsum, hsum);

    kb_kernel<<<N_GRAPHS * T_CAPS / 4, 256, 0, stream>>>(hsum, hc_part, csum_part, W, WT, bias,
                                                          xsum, ab, gstart, wva, bva, out, 0);
    ka_fused_kernel<<<N_GRAPHS * NSPLIT, 256, 0, stream>>>(h16, gstart, wva, bva, wvb, bvb,
                                                            hc_part, csum_part, 0);
    kb_kernel<<<N_GRAPHS * T_CAPS / 4, 256, 0, stream>>>(hsum, hc_part, csum_part, W, WT, bias,
                                                          xsum, ab, gstart, wvb, bvb, out, 1);
    ka_fused_kernel<<<N_GRAPHS * NSPLIT, 256, 0, stream>>>(h16, gstart, wva, bva, wvb, bvb,
                                                            hc_part, csum_part, 1);
    kb_kernel<<<N_GRAPHS * T_CAPS / 4, 256, 0, stream>>>(hsum, hc_part, csum_part, W, WT, bias,
                                                          xsum, ab, gstart, wva, bva, out, 2);
}